// Round 2
// baseline (265.809 us; speedup 1.0000x reference)
//
#include <hip/hip_runtime.h>
#include <math.h>

#define B_ 128
#define G_ 16
#define A_ 8732
#define C_ 21
#define THR_ 0.5f
#define NEG_POS_ 3
#define VAR0_ 0.1f
#define VAR1_ 0.2f

#define CHUNK_  512
#define NCHUNK_ ((A_ + CHUNK_ - 1) / CHUNK_)    // 18 (17 full + 28-anchor tail)
#define TAILA_  (A_ - (NCHUNK_ - 1) * CHUNK_)   // 28
#define FULLV_  (CHUNK_ * C_ / 4)               // 2688 float4 per full chunk
#define TAILV_  (TAILA_ * C_ / 4)               // 147 float4 (588 floats, exact)
#define NPT_    NCHUNK_                          // aux values per thread (18)

// ---------------------------------------------------------------------------
// K_A: fully fused per-batch kernel. One 512-thread block per batch.
//   Phase 1: IoU matching (identical logic to the verified k_match).
//   Phase 2: softmax/nll loss, conf streamed via coalesced LDS staging chunks.
//            match codes read straight from LDS (never hit global).
//   Phase 3: hard-negative mining binary search on register-resident aux
//            (aux lives only in LDS, never in global).
// Per-batch partials (loc, cls, npos) -> tiny global arrays; no atomics.
// ---------------------------------------------------------------------------
__global__ __launch_bounds__(512) void k_fused(
    const float* __restrict__ pred_off,   // B,A,4
    const float* __restrict__ pred_conf,  // B,A,C
    const float* __restrict__ tboxes,     // B,G,4 (point form)
    const int*   __restrict__ tlabels,    // B,G
    const float* __restrict__ anchors,    // A,4 (center form)
    float*       __restrict__ lloc_b,     // B
    float*       __restrict__ lcls_b,     // B
    int*         __restrict__ npos_b)     // B
{
    const int b    = blockIdx.x;
    const int tid  = threadIdx.x;
    const int lane = tid & 63;
    const int w    = tid >> 6;            // 0..7

    __shared__ float         s_ov[A_];                 // 34928 B
    __shared__ unsigned char s_gi[A_];                 //  8732 B
    __shared__ float         s_aux[A_];                // 34928 B
    __shared__ float4        s_stage[FULLV_];          // 43008 B
    __shared__ float s_boxlds[G_ * 4];
    __shared__ int   s_lab[G_];
    __shared__ unsigned long long s_gb[8 * G_];
    __shared__ int   s_forced[G_];
    __shared__ int   s_cnt[8];
    __shared__ int   s_c[2][8];
    __shared__ float s_r0[8], s_r1[8], s_r3[8];
    __shared__ int   s_r2[8];

    // ---------------- Phase 1: matching (verified logic) ----------------
    if (tid < G_ * 4) s_boxlds[tid] = tboxes[b * G_ * 4 + tid];
    if (tid < G_)     s_lab[tid]    = tlabels[b * G_ + tid];
    __syncthreads();

    float bx0[G_], by0[G_], bx1[G_], by1[G_], bar[G_];
    #pragma unroll
    for (int g = 0; g < G_; ++g) {
        bx0[g] = s_boxlds[g * 4 + 0];
        by0[g] = s_boxlds[g * 4 + 1];
        bx1[g] = s_boxlds[g * 4 + 2];
        by1[g] = s_boxlds[g * 4 + 3];
        bar[g] = (bx1[g] - bx0[g]) * (by1[g] - by0[g]);
    }

    unsigned long long gb[G_];
    #pragma unroll
    for (int g = 0; g < G_; ++g) gb[g] = 0ull;

    for (int a = tid; a < A_; a += 512) {
        float4 an = ((const float4*)anchors)[a];
        float ax0 = an.x - an.z * 0.5f, ay0 = an.y - an.w * 0.5f;
        float ax1 = an.x + an.z * 0.5f, ay1 = an.y + an.w * 0.5f;
        float area_b = (ax1 - ax0) * (ay1 - ay0);
        float bov = -1.f; int bg = 0;
        #pragma unroll
        for (int g = 0; g < G_; ++g) {
            float tlx = fmaxf(bx0[g], ax0);
            float tly = fmaxf(by0[g], ay0);
            float brx = fminf(bx1[g], ax1);
            float bry = fminf(by1[g], ay1);
            float wdt = fmaxf(brx - tlx, 0.f);
            float hgt = fmaxf(bry - tly, 0.f);
            float inter = wdt * hgt;
            float iou = inter / (bar[g] + area_b - inter);
            if (iou > bov) { bov = iou; bg = g; }   // first g wins on ties
            unsigned long long pk =
                ((unsigned long long)__float_as_uint(iou) << 32) |
                (unsigned)(~(unsigned)a);           // max iou, min a on ties
            if (pk > gb[g]) gb[g] = pk;
        }
        s_ov[a] = bov;
        s_gi[a] = (unsigned char)bg;
    }

    #pragma unroll
    for (int g = 0; g < G_; ++g) {
        #pragma unroll
        for (int off = 32; off > 0; off >>= 1) {
            unsigned long long o = __shfl_down(gb[g], off);
            if (o > gb[g]) gb[g] = o;
        }
    }
    if (lane == 0) {
        #pragma unroll
        for (int g = 0; g < G_; ++g) s_gb[w * G_ + g] = gb[g];
    }
    __syncthreads();
    if (tid < G_) {
        unsigned long long m = 0ull;
        #pragma unroll
        for (int wv = 0; wv < 8; ++wv) {
            unsigned long long v = s_gb[wv * G_ + tid];
            if (v > m) m = v;
        }
        s_forced[tid] = (int)(~(unsigned)(m & 0xFFFFFFFFull));
    }
    __syncthreads();
    if (tid == 0) {
        for (int g = 0; g < G_; ++g) {      // ascending g, last write wins
            int a = s_forced[g];
            s_ov[a] = 1.0f;
            s_gi[a] = (unsigned char)g;
        }
    }
    // barrier provided at the top of the first chunk iteration below

    // ---------------- Phase 2: loss via staged conf chunks ----------------
    float lloc = 0.f, pnll = 0.f;
    int   cnt  = 0;

    for (int cc = 0; cc < NCHUNK_; ++cc) {
        const int nv = (cc == NCHUNK_ - 1) ? TAILV_ : FULLV_;
        __syncthreads();   // previous chunk's compute done (and phase-1 LDS final)
        const float4* g4 = (const float4*)pred_conf
                         + ((((size_t)b * A_) + (size_t)cc * CHUNK_) * C_ >> 2);
        for (int idx = tid; idx < nv; idx += 512) s_stage[idx] = g4[idx];
        __syncthreads();

        const int a = cc * CHUNK_ + tid;
        float auxv = 0.f;
        if (a < A_) {
            const float* sc = (const float*)s_stage + tid * C_;  // stride 21: conflict-free
            float m = sc[0];
            #pragma unroll
            for (int c = 1; c < C_; ++c) m = fmaxf(m, sc[c]);
            float s = 0.f;
            #pragma unroll
            for (int c = 0; c < C_; ++c) s += __expf(sc[c] - m);
            float lse = m + __logf(s);

            float ov  = s_ov[a];
            int   g   = s_gi[a];
            int  conf = (ov < THR_) ? 0 : (s_lab[g] + 1);
            float xc  = sc[conf];                 // single dynamic LDS read
            float nll = lse - xc;
            bool  pos = conf > 0;
            auxv = pos ? 0.f : nll;

            if (pos) {
                cnt++;
                pnll += nll;
                float4 an = ((const float4*)anchors)[a];
                float bxx0 = s_boxlds[g * 4 + 0], bxy0 = s_boxlds[g * 4 + 1];
                float bxx1 = s_boxlds[g * 4 + 2], bxy1 = s_boxlds[g * 4 + 3];
                float gcx = (bxx0 + bxx1) * 0.5f, gcy = (bxy0 + bxy1) * 0.5f;
                float gw = bxx1 - bxx0, gh = bxy1 - bxy0;
                float l0 = (gcx - an.x) / (an.z * VAR0_);
                float l1 = (gcy - an.y) / (an.w * VAR0_);
                float l2 = logf(gw / an.z) / VAR1_;
                float l3 = logf(gh / an.w) / VAR1_;
                float4 p = ((const float4*)pred_off)[(size_t)b * A_ + a];
                float d, ad;
                d = p.x - l0; ad = fabsf(d); lloc += (ad < 1.f) ? 0.5f * d * d : ad - 0.5f;
                d = p.y - l1; ad = fabsf(d); lloc += (ad < 1.f) ? 0.5f * d * d : ad - 0.5f;
                d = p.z - l2; ad = fabsf(d); lloc += (ad < 1.f) ? 0.5f * d * d : ad - 0.5f;
                d = p.w - l3; ad = fabsf(d); lloc += (ad < 1.f) ? 0.5f * d * d : ad - 0.5f;
            }
        }
        if (a < A_) s_aux[a] = auxv;
    }

    // npos reduce (needed before selection)
    {
        int c = cnt;
        #pragma unroll
        for (int off = 32; off > 0; off >>= 1) c += __shfl_down(c, off);
        if (lane == 0) s_cnt[w] = c;
    }
    __syncthreads();
    int npos = 0;
    #pragma unroll
    for (int wv = 0; wv < 8; ++wv) npos += s_cnt[wv];
    if (tid == 0) npos_b[b] = npos;
    const int K = min(NEG_POS_ * npos, A_ - 1);

    // ---------------- Phase 3: hard-negative mining ----------------
    unsigned u[NPT_];
    #pragma unroll
    for (int j = 0; j < NPT_; ++j) {
        int a = tid + j * 512;
        u[j] = (a < A_) ? __float_as_uint(s_aux[a]) : 0u;
    }

    unsigned lo = 0u, hi = 0x7f800000u;
    int it = 0;
    while (lo < hi) {
        unsigned mid = (lo + hi) >> 1;
        int c = 0;
        #pragma unroll
        for (int j = 0; j < NPT_; ++j) c += (u[j] > mid);
        #pragma unroll
        for (int off = 32; off > 0; off >>= 1) c += __shfl_down(c, off);
        if (lane == 0) s_c[it & 1][w] = c;
        __syncthreads();
        int total = 0;
        #pragma unroll
        for (int wv = 0; wv < 8; ++wv) total += s_c[it & 1][wv];
        if (total >= K) lo = mid + 1; else hi = mid;
        ++it;
    }
    // lo == bit pattern of T = K-th largest aux value

    int selc = 0; float selsm = 0.f;
    #pragma unroll
    for (int j = 0; j < NPT_; ++j) {
        if (u[j] > lo) { selc++; selsm += __uint_as_float(u[j]); }
    }

    // ---------------- combined final reduce ----------------
    #pragma unroll
    for (int off = 32; off > 0; off >>= 1) {
        lloc  += __shfl_down(lloc, off);
        pnll  += __shfl_down(pnll, off);
        selc  += __shfl_down(selc, off);
        selsm += __shfl_down(selsm, off);
    }
    if (lane == 0) { s_r0[w] = lloc; s_r1[w] = pnll; s_r2[w] = selc; s_r3[w] = selsm; }
    __syncthreads();
    if (tid == 0) {
        float L = 0.f, P = 0.f, S = 0.f; int Cc = 0;
        #pragma unroll
        for (int wv = 0; wv < 8; ++wv) {
            L += s_r0[wv]; P += s_r1[wv]; Cc += s_r2[wv]; S += s_r3[wv];
        }
        float T = __uint_as_float(lo);
        lloc_b[b] = L;
        lcls_b[b] = P + S + (float)(K - Cc) * T;
    }
}

// ---------------------------------------------------------------------------
// K_B: finalize — reduce 128 per-batch partials. 2 waves.
// ---------------------------------------------------------------------------
__global__ __launch_bounds__(128) void k_fin(
    const float* __restrict__ lloc_b,
    const float* __restrict__ lcls_b,
    const int*   __restrict__ npos_b,
    float*       __restrict__ out)
{
    const int tid  = threadIdx.x;
    const int lane = tid & 63;
    const int w    = tid >> 6;
    __shared__ float s_l[2], s_c[2];
    __shared__ int   s_n[2];

    float L = lloc_b[tid];
    float Cc = lcls_b[tid];
    int   n = npos_b[tid];
    #pragma unroll
    for (int off = 32; off > 0; off >>= 1) {
        L  += __shfl_down(L, off);
        Cc += __shfl_down(Cc, off);
        n  += __shfl_down(n, off);
    }
    if (lane == 0) { s_l[w] = L; s_c[w] = Cc; s_n[w] = n; }
    __syncthreads();
    if (tid == 0) {
        float ntot = (float)(s_n[0] + s_n[1]);
        out[0] = (s_l[0] + s_l[1]) / ntot;
        out[1] = (s_c[0] + s_c[1]) / ntot;
    }
}

// ---------------------------------------------------------------------------
extern "C" void kernel_launch(void* const* d_in, const int* in_sizes, int n_in,
                              void* d_out, int out_size, void* d_ws, size_t ws_size,
                              hipStream_t stream) {
    const float* pred_off  = (const float*)d_in[0];  // B,A,4
    const float* pred_conf = (const float*)d_in[1];  // B,A,C
    const float* tboxes    = (const float*)d_in[2];  // B,G,4
    const int*   tlabels   = (const int*)  d_in[3];  // B,G
    const float* anchors   = (const float*)d_in[4];  // A,4
    float* out = (float*)d_out;

    // workspace: three tiny per-batch arrays (16B-aligned)
    char* ws = (char*)d_ws;
    float* lloc_ws = (float*)ws;  ws += (size_t)B_ * sizeof(float);
    float* lcls_ws = (float*)ws;  ws += (size_t)B_ * sizeof(float);
    int*   npos_ws = (int*)ws;

    k_fused<<<B_, 512, 0, stream>>>(pred_off, pred_conf, tboxes, tlabels, anchors,
                                    lloc_ws, lcls_ws, npos_ws);
    k_fin<<<1, 128, 0, stream>>>(lloc_ws, lcls_ws, npos_ws, out);
}